// Round 1
// baseline (12760.876 us; speedup 1.0000x reference)
//
#include <hip/hip_runtime.h>

// Seq2Seq LSTM (enc 8192 steps, dec 4096 autoregressive steps), H=128, fp32.
// Latency-bound sequential recurrence -> single workgroup, 512 threads.
// Thread t = 4k+g owns gate row g*128+k; Whh row in 128 VGPRs.
// h double-buffered in LDS; ONE __syncthreads per step.

#define H      128
#define ENC_T  8192
#define DEC_T  4096
#define NT     512

__device__ __forceinline__ float sigm(float x) {
    // 1/(1+exp(-x)); v_exp + v_rcp, ~1-2 ulp. Saturates correctly at +-inf.
    return __builtin_amdgcn_rcpf(1.0f + __expf(-x));
}
__device__ __forceinline__ float tanhfast(float x) {
    // tanh(x) = 1 - 2/(1+exp(2x)); exp overflow -> inf -> rcp -> 0 -> +1 (correct).
    return 1.0f - 2.0f * __builtin_amdgcn_rcpf(1.0f + __expf(2.0f * x));
}

__global__ __launch_bounds__(NT, 2)
void seq2seq_lstm(const float* __restrict__ input_seq,
                  const float* __restrict__ enc_Wih,
                  const float* __restrict__ enc_Whh,
                  const float* __restrict__ enc_bih,
                  const float* __restrict__ enc_bhh,
                  const float* __restrict__ dec_Wih,
                  const float* __restrict__ dec_Whh,
                  const float* __restrict__ dec_bih,
                  const float* __restrict__ dec_bhh,
                  const float* __restrict__ fc_W,
                  const float* __restrict__ fc_b,
                  float* __restrict__ out)
{
    __shared__ float4 xin4[ENC_T / 4];     // staged input sequence (32 KB)
    __shared__ float4 hbuf4[2][H / 4];     // double-buffered hidden state

    const int tid  = threadIdx.x;          // 0..511
    const int k    = tid >> 2;             // hidden unit 0..127
    const int g    = tid & 3;              // gate: 0=i 1=f 2=g 3=o (PyTorch order)
    const int row  = g * H + k;            // row of the [4H, H] weight matrices
    const int lane = tid & 63;

    // Stage input sequence into LDS (coalesced float4), zero h.
    const float4* in4 = (const float4*)input_seq;
    for (int i = tid; i < ENC_T / 4; i += NT) xin4[i] = in4[i];
    if (tid < H / 4) hbuf4[0][tid] = make_float4(0.f, 0.f, 0.f, 0.f);

    // Encoder weights: my Whh row into registers (32 x float4 = 128 VGPRs).
    float4 w[H / 4];
    {
        const float4* Wr = (const float4*)(enc_Whh + row * H);
#pragma unroll
        for (int j = 0; j < H / 4; ++j) w[j] = Wr[j];
    }
    float bias = enc_bih[row] + enc_bhh[row];
    float wih  = enc_Wih[row];             // [4H,1] column

    float c  = 0.f;                        // cell state, replicated in all 4 lanes of group
    int  cur = 0;
    __syncthreads();

    const float* xin = (const float*)xin4;

    // ---------------- encoder: 8192 steps ----------------
    for (int step = 0; step < ENC_T; ++step) {
        const float x = xin[step];
        float a0 = fmaf(wih, x, bias), a1 = 0.f, a2 = 0.f, a3 = 0.f;
        const float4* hb = (const float4*)hbuf4[cur];
#pragma unroll
        for (int j = 0; j < H / 4; ++j) {  // 32x ds_read_b128 (broadcast) + 128 FMA
            const float4 hv = hb[j];
            a0 = fmaf(w[j].x, hv.x, a0);
            a1 = fmaf(w[j].y, hv.y, a1);
            a2 = fmaf(w[j].z, hv.z, a2);
            a3 = fmaf(w[j].w, hv.w, a3);
        }
        const float acc = (a0 + a1) + (a2 + a3);

        // Gather the 4 gates of unit k (adjacent lanes), update redundantly.
        const int base = lane & ~3;
        const float vi = __shfl(acc, base + 0, 64);
        const float vf = __shfl(acc, base + 1, 64);
        const float vg = __shfl(acc, base + 2, 64);
        const float vo = __shfl(acc, base + 3, 64);
        c = sigm(vf) * c + sigm(vi) * tanhfast(vg);
        const float hn = sigm(vo) * tanhfast(c);

        cur ^= 1;
        if (g == 0) ((float*)hbuf4[cur])[k] = hn;
        __syncthreads();                   // single barrier per step (double buffer)
    }

    // ---------------- switch to decoder weights ----------------
    {
        const float4* Wr = (const float4*)(dec_Whh + row * H);
#pragma unroll
        for (int j = 0; j < H / 4; ++j) w[j] = Wr[j];
    }
    bias = dec_bih[row] + dec_bhh[row];
    wih  = dec_Wih[row];
    const float fw0 = fc_W[2 * lane];
    const float fw1 = fc_W[2 * lane + 1];
    const float fcb = fc_b[0];

    float y = 0.f;                         // autoregressive input, starts at 0

    // ---------------- decoder: 4096 steps ----------------
    for (int step = 0; step < DEC_T; ++step) {
        float a0 = fmaf(wih, y, bias), a1 = 0.f, a2 = 0.f, a3 = 0.f;
        const float4* hb = (const float4*)hbuf4[cur];
#pragma unroll
        for (int j = 0; j < H / 4; ++j) {
            const float4 hv = hb[j];
            a0 = fmaf(w[j].x, hv.x, a0);
            a1 = fmaf(w[j].y, hv.y, a1);
            a2 = fmaf(w[j].z, hv.z, a2);
            a3 = fmaf(w[j].w, hv.w, a3);
        }
        const float acc = (a0 + a1) + (a2 + a3);

        const int base = lane & ~3;
        const float vi = __shfl(acc, base + 0, 64);
        const float vf = __shfl(acc, base + 1, 64);
        const float vg = __shfl(acc, base + 2, 64);
        const float vo = __shfl(acc, base + 3, 64);
        c = sigm(vf) * c + sigm(vi) * tanhfast(vg);
        const float hn = sigm(vo) * tanhfast(c);

        cur ^= 1;
        if (g == 0) ((float*)hbuf4[cur])[k] = hn;
        __syncthreads();

        // pred = fc_W @ h_new + fc_b, computed redundantly per wave:
        // lane l covers h[2l], h[2l+1]; 6-step butterfly -> identical in all lanes.
        const float* hf = (const float*)hbuf4[cur];
        float p = fmaf(fw0, hf[2 * lane], fw1 * hf[2 * lane + 1]);
#pragma unroll
        for (int m = 32; m >= 1; m >>= 1) p += __shfl_xor(p, m, 64);
        y = p + fcb;
        if (tid == 0) out[step] = y;
    }
}

extern "C" void kernel_launch(void* const* d_in, const int* in_sizes, int n_in,
                              void* d_out, int out_size, void* d_ws, size_t ws_size,
                              hipStream_t stream)
{
    (void)in_sizes; (void)n_in; (void)d_ws; (void)ws_size; (void)out_size;
    seq2seq_lstm<<<1, NT, 0, stream>>>(
        (const float*)d_in[0],   // input_seq
        (const float*)d_in[1],   // enc_Wih
        (const float*)d_in[2],   // enc_Whh
        (const float*)d_in[3],   // enc_bih
        (const float*)d_in[4],   // enc_bhh
        (const float*)d_in[5],   // dec_Wih
        (const float*)d_in[6],   // dec_Whh
        (const float*)d_in[7],   // dec_bih
        (const float*)d_in[8],   // dec_bhh
        (const float*)d_in[9],   // fc_W
        (const float*)d_in[10],  // fc_b
        (float*)d_out);
}